// Round 5
// baseline (498.498 us; speedup 1.0000x reference)
//
#include <hip/hip_runtime.h>
#include <hip/hip_bf16.h>

typedef __attribute__((ext_vector_type(8))) short bf16x8;
typedef __attribute__((ext_vector_type(4))) float f32x4;

#define DEVFN static __device__ __forceinline__

constexpr int kSQ = 2048, kSKV = 2048, kD = 1024, kH = 16;
constexpr int kM = 4 * kSQ;   // 8192 query rows (B*SQ)

DEVFN unsigned short f2bf(float f) {
  union { float f; unsigned u; } v; v.f = f;
  unsigned r = v.u + 0x7FFFu + ((v.u >> 16) & 1u);
  return (unsigned short)(r >> 16);
}
DEVFN float bf2f(unsigned short h) {
  union { unsigned u; float f; } v; v.u = ((unsigned)h) << 16; return v.f;
}
DEVFN unsigned cvtpk(float lo, float hi) {
  unsigned r;
  asm("v_cvt_pk_bf16_f32 %0, %1, %2" : "=v"(r) : "v"(lo), "v"(hi));
  return r;
}
DEVFN float vexp2(float x) {
  float r;
  asm("v_exp_f32 %0, %1" : "=v"(r) : "v"(x));
  return r;
}

DEVFN void gload16(const void* g, void* l) {
  __builtin_amdgcn_global_load_lds(
      (const __attribute__((address_space(1))) unsigned int*)g,
      (__attribute__((address_space(3))) unsigned int*)l, 16, 0, 0);
}

// ---------------------------------------------------------------------------
// Kernel 1 (merged): blocks [0, 2*kM): activation fp32->bf16 + LoRA-down dots.
// blocks [2*kM, 2*kM+1024): weight convert+transpose (4 weights x 256 tiles).
__global__ __launch_bounds__(256) void k_prep_wt(
    const float* __restrict__ hs, const float* __restrict__ enc,
    const float* __restrict__ qdn, const float* __restrict__ kdn,
    const float* __restrict__ vdn,
    const float* __restrict__ Wq, const float* __restrict__ Wk,
    const float* __restrict__ Wv, const float* __restrict__ Wo,
    unsigned short* __restrict__ hsb, unsigned short* __restrict__ encb,
    float* __restrict__ tq, float* __restrict__ tkv,
    unsigned short* __restrict__ Wqt, unsigned short* __restrict__ Wkvt,
    unsigned short* __restrict__ Wot) {
  __shared__ float red[4][8];
  __shared__ unsigned short tile[64][65];
  const int bid = blockIdx.x;
  const int tid = threadIdx.x;

  if (bid < 2 * kM) {
    const bool isH = bid < kM;
    const int rr = isH ? bid : bid - kM;
    const float* srcRow = (isH ? hs : enc) + (size_t)rr * kD;
    unsigned short* dstRow = (isH ? hsb : encb) + (size_t)rr * kD;

    float4 x = reinterpret_cast<const float4*>(srcRow)[tid];
    short4 o;
    o.x = (short)f2bf(x.x); o.y = (short)f2bf(x.y);
    o.z = (short)f2bf(x.z); o.w = (short)f2bf(x.w);
    *reinterpret_cast<short4*>(dstRow + tid * 4) = o;

    float xs[4] = {x.x, x.y, x.z, x.w};
    float a[4] = {0.f, 0.f, 0.f, 0.f};
    float bacc[4] = {0.f, 0.f, 0.f, 0.f};
    const float* dnA = isH ? qdn : kdn;
    const int base = tid * 4;
#pragma unroll
    for (int e = 0; e < 4; ++e) {
      const float* dr = dnA + (size_t)(base + e) * 4;
      a[0] += xs[e] * dr[0]; a[1] += xs[e] * dr[1];
      a[2] += xs[e] * dr[2]; a[3] += xs[e] * dr[3];
    }
    if (!isH) {
#pragma unroll
      for (int e = 0; e < 4; ++e) {
        const float* dr = vdn + (size_t)(base + e) * 4;
        bacc[0] += xs[e] * dr[0]; bacc[1] += xs[e] * dr[1];
        bacc[2] += xs[e] * dr[2]; bacc[3] += xs[e] * dr[3];
      }
    }
    const int l = tid & 63, w = tid >> 6;
    float vals[8] = {a[0], a[1], a[2], a[3], bacc[0], bacc[1], bacc[2], bacc[3]};
#pragma unroll
    for (int k2 = 0; k2 < 8; ++k2) {
      float v = vals[k2];
#pragma unroll
      for (int m = 1; m < 64; m <<= 1) v += __shfl_xor(v, m);
      if (l == 0) red[w][k2] = v;
    }
    __syncthreads();
    if (tid < 8) {
      float s = red[0][tid] + red[1][tid] + red[2][tid] + red[3][tid];
      if (isH) {
        if (tid < 4) tq[(size_t)rr * 4 + tid] = s;
      } else {
        tkv[(size_t)rr * 8 + tid] = s;   // 0..3 = k-down, 4..7 = v-down
      }
    }
  } else {
    const int t = bid - 2 * kM;
    const int wid = t >> 8, tt = t & 255;
    const float* W = (wid == 0) ? Wq : (wid == 1) ? Wk : (wid == 2) ? Wv : Wo;
    unsigned short* Wt = (wid == 0) ? Wqt : (wid == 1) ? Wkvt
                        : (wid == 2) ? (Wkvt + (size_t)1024 * 1024) : Wot;
    const int tk0 = (tt & 15) * 64;
    const int tn0 = (tt >> 4) * 64;
    for (int i = tid; i < 4096; i += 256) {
      int r = i >> 6, c = i & 63;
      tile[r][c] = f2bf(W[(size_t)(tk0 + r) * 1024 + tn0 + c]);
    }
    __syncthreads();
    for (int i = tid; i < 4096; i += 256) {
      int r = i >> 6, c = i & 63;
      Wt[(size_t)(tn0 + r) * 1024 + tk0 + c] = tile[c][r];
    }
  }
}

// ---------------------------------------------------------------------------
// Register-only GEMM main loop: no LDS, no barriers. Fragments loaded straight
// from global (A rows coalesce as 64B segments across lane quads; B is 2MB
// L2-resident). 2-deep register double-buffer; latency hidden by 12 waves/CU.
#define RLOAD(aset, bset, k0)                                               \
  do {                                                                      \
    _Pragma("unroll")                                                       \
    for (int m = 0; m < 4; ++m)                                             \
      aset[m] = *(const bf16x8*)(Aw + (size_t)(m * 16) * 1024 + (k0));      \
    _Pragma("unroll")                                                       \
    for (int n = 0; n < 4; ++n)                                             \
      bset[n] = *(const bf16x8*)(Bw + (size_t)(n * 16) * 1024 + (k0));      \
  } while (0)

#define RMFMA(aset, bset)                                                   \
  do {                                                                      \
    _Pragma("unroll")                                                       \
    for (int m = 0; m < 4; ++m)                                             \
      _Pragma("unroll")                                                     \
      for (int n = 0; n < 4; ++n)                                           \
        acc[m][n] = __builtin_amdgcn_mfma_f32_16x16x32_bf16(                \
            aset[m], bset[n], acc[m][n], 0, 0, 0);                          \
  } while (0)

#define RGEMM_LOOP()                                                        \
  bf16x8 a0[4], b0[4], a1[4], b1[4];                                        \
  RLOAD(a0, b0, 0);                                                         \
  for (int kt = 0; kt < 32; kt += 2) {                                      \
    RLOAD(a1, b1, (kt + 1) * 32);                                           \
    RMFMA(a0, b0);                                                          \
    if (kt + 2 < 32) RLOAD(a0, b0, (kt + 2) * 32);                          \
    RMFMA(a1, b1);                                                          \
  }

// Kernel 2: merged QKV projection GEMM. blocks [0,512): Q; [512,1536): K|V.
__global__ __launch_bounds__(256) void k_gemm_qkv(
    const unsigned short* __restrict__ hsb, const unsigned short* __restrict__ encb,
    const unsigned short* __restrict__ Wqt, const unsigned short* __restrict__ Wkvt,
    const float* __restrict__ tq, const float* __restrict__ tkv,
    const float* __restrict__ q_up, const float* __restrict__ k_up,
    const float* __restrict__ v_up,
    unsigned short* __restrict__ Qhp, unsigned short* __restrict__ Khp,
    unsigned short* __restrict__ Vhp) {
  const int tid = threadIdx.x;
  const int l = tid & 63, w = tid >> 6;
  const int bid = blockIdx.x;

  const unsigned short *A, *Bt;
  const float *tmat, *up;
  unsigned short* dst;
  int m0, nB0, nOut0, tstr;
  if (bid < 512) {
    const int rid = (bid & 7) * 64 + (bid >> 3);
    nB0 = (rid & 7) * 128; m0 = (rid >> 3) * 128;
    A = hsb; Bt = Wqt; tmat = tq; tstr = 4; up = q_up; dst = Qhp; nOut0 = nB0;
  } else {
    const int b2 = bid - 512;
    const int rid = (b2 & 7) * 128 + (b2 >> 3);
    nB0 = (rid & 15) * 128; m0 = (rid >> 4) * 128;
    A = encb; Bt = Wkvt; tstr = 8;
    if (nB0 < 1024) { tmat = tkv;     up = k_up; dst = Khp; nOut0 = nB0; }
    else            { tmat = tkv + 4; up = v_up; dst = Vhp; nOut0 = nB0 - 1024; }
  }
  const int wr = (w >> 1) * 64, wc = (w & 1) * 64;
  const int lr = l & 15, lk = l >> 4;

  const unsigned short* Aw = A  + (size_t)(m0  + wr + lr) * 1024 + lk * 8;
  const unsigned short* Bw = Bt + (size_t)(nB0 + wc + lr) * 1024 + lk * 8;

  f32x4 acc[4][4];
  const f32x4 zero = {0.f, 0.f, 0.f, 0.f};
#pragma unroll
  for (int m = 0; m < 4; ++m)
#pragma unroll
    for (int n = 0; n < 4; ++n) acc[m][n] = zero;

  RGEMM_LOOP()

#pragma unroll
  for (int n = 0; n < 4; ++n) {
    const int gcol = nOut0 + wc + n * 16 + lr;
    const float u0 = up[gcol], u1 = up[1024 + gcol];
    const float u2 = up[2048 + gcol], u3 = up[3072 + gcol];
#pragma unroll
    for (int m = 0; m < 4; ++m) {
#pragma unroll
      for (int r = 0; r < 4; ++r) {
        const int grow = m0 + wr + m * 16 + lk * 4 + r;
        const float4 tt = *reinterpret_cast<const float4*>(tmat + (size_t)grow * tstr);
        const float val = acc[m][n][r] + tt.x * u0 + tt.y * u1 + tt.z * u2 + tt.w * u3;
        const int b = grow >> 11, s = grow & 2047;
        const int h = gcol >> 6, d = gcol & 63;
        dst[(((size_t)(b * kH + h)) * 2048 + s) * 64 + d] = f2bf(val);
      }
    }
  }
}

// Kernel 3: final GEMM  out = Ob @ Wot^T + bias + t_o @ o_up  (f32 output)
__global__ __launch_bounds__(256) void k_gemm_out(
    const unsigned short* __restrict__ A, const unsigned short* __restrict__ Bt,
    const float* __restrict__ tmat, const float* __restrict__ up,
    const float* __restrict__ bias, float* __restrict__ outp) {
  const int tid = threadIdx.x;
  const int l = tid & 63, w = tid >> 6;
  const int bid = blockIdx.x;
  const int rid = (bid & 7) * 64 + (bid >> 3);
  const int nB0 = (rid & 7) * 128, m0 = (rid >> 3) * 128;
  const int wr = (w >> 1) * 64, wc = (w & 1) * 64;
  const int lr = l & 15, lk = l >> 4;

  const unsigned short* Aw = A  + (size_t)(m0  + wr + lr) * 1024 + lk * 8;
  const unsigned short* Bw = Bt + (size_t)(nB0 + wc + lr) * 1024 + lk * 8;

  f32x4 acc[4][4];
  const f32x4 zero = {0.f, 0.f, 0.f, 0.f};
#pragma unroll
  for (int m = 0; m < 4; ++m)
#pragma unroll
    for (int n = 0; n < 4; ++n) acc[m][n] = zero;

  RGEMM_LOOP()

#pragma unroll
  for (int n = 0; n < 4; ++n) {
    const int gcol = nB0 + wc + n * 16 + lr;
    const float u0 = up[gcol], u1 = up[1024 + gcol];
    const float u2 = up[2048 + gcol], u3 = up[3072 + gcol];
    const float bz = bias[gcol];
#pragma unroll
    for (int m = 0; m < 4; ++m) {
#pragma unroll
      for (int r = 0; r < 4; ++r) {
        const int grow = m0 + wr + m * 16 + lk * 4 + r;
        const float4 tt = *reinterpret_cast<const float4*>(tmat + (size_t)grow * 4);
        outp[(size_t)grow * 1024 + gcol] =
            acc[m][n][r] + tt.x * u0 + tt.y * u1 + tt.z * u2 + tt.w * u3 + bz;
      }
    }
  }
}

// ---------------------------------------------------------------------------
// Kernel 4: V head-layout transpose: (bh, s, d) -> (bh, d, s)
__global__ __launch_bounds__(256) void k_vt(const unsigned short* __restrict__ Vh,
                                            unsigned short* __restrict__ Vt) {
  __shared__ unsigned short tile[64][65];
  const int bh = blockIdx.y;
  const int s0 = blockIdx.x * 64;
  const unsigned short* src = Vh + ((size_t)bh * kSKV + s0) * 64;
  for (int i = threadIdx.x; i < 4096; i += 256) {
    int r = i >> 6, c = i & 63;
    tile[r][c] = src[(size_t)r * 64 + c];
  }
  __syncthreads();
  unsigned short* dst = Vt + (size_t)bh * 64 * kSKV + s0;
  for (int i = threadIdx.x; i < 4096; i += 256) {
    int r = i >> 6, c = i & 63;
    dst[(size_t)r * kSKV + c] = tile[c][r];
  }
}

// ---------------------------------------------------------------------------
// Kernel 5: flash attention, QBLK=128 (4 waves x 32 q-rows), KV tiles of 64.
// Fixed-max softmax via exp2 (Q pre-scaled by log2e/8). Conflict-free
// 16B-unit XOR swizzle on K/V/P. (round-3 structure: dbuf + syncthreads)
__global__ __launch_bounds__(256) void k_attn(
    const unsigned short* __restrict__ Qh, const unsigned short* __restrict__ Kh,
    const unsigned short* __restrict__ Vt, unsigned short* __restrict__ Obf) {
  __shared__ unsigned short lK[2][4096];
  __shared__ unsigned short lV[2][4096];
  __shared__ __align__(16) unsigned short lP[4][1024];

  const int bid = blockIdx.x + 16 * blockIdx.y;              // 1024 blocks
  const int rid = (bid & 7) * 128 + (bid >> 3);
  const int q0 = (rid & 15) * 128;
  const int bh = rid >> 4;

  const int tid = threadIdx.x;
  const int l = tid & 63, w = tid >> 6;
  const int lr = l & 15, lk = l >> 4;
  const int m7 = lr & 7;
  const int lkh = lk >> 1, lkb = lk & 1;

  const unsigned short* Qb = Qh + (size_t)bh * kSQ * 64;
  const unsigned short* Kb = Kh + (size_t)bh * kSKV * 64;
  const unsigned short* Vb = Vt + (size_t)bh * 64 * kSKV;

  // Q fragments pre-scaled by log2(e)/8 (exp2-form softmax)
  const float QS = 0.125f * 1.4426950408889634f;
  bf16x8 qf[2][2];
#pragma unroll
  for (int m = 0; m < 2; ++m)
#pragma unroll
    for (int kk = 0; kk < 2; ++kk) {
      bf16x8 v = *(const bf16x8*)
          &Qb[(size_t)(q0 + w * 32 + m * 16 + lr) * 64 + kk * 32 + lk * 8];
#pragma unroll
      for (int j = 0; j < 8; ++j) {
        unsigned short u = (unsigned short)v[j];
        v[j] = (short)f2bf(bf2f(u) * QS);
      }
      qf[m][kk] = v;
    }

  f32x4 oacc[2][4];
  const f32x4 zero = {0.f, 0.f, 0.f, 0.f};
#pragma unroll
  for (int m = 0; m < 2; ++m)
#pragma unroll
    for (int n = 0; n < 4; ++n) oacc[m][n] = zero;
  float lrow[2] = {0.f, 0.f};

  const int sr8 = l >> 3;
  const int su = (l & 7) ^ sr8;
  unsigned short* lPw = lP[w];

#define ASTAGE(dbuf, tile) do { \
    _Pragma("unroll") for (int cc = 0; cc < 2; ++cc) { \
      const int c = 2 * w + cc; const int row = c * 8 + sr8; \
      gload16(Kb + (size_t)((tile) * 64 + row) * 64 + su * 8, &lK[dbuf][c * 512]); \
      gload16(Vb + (size_t)row * kSKV + (tile) * 64 + su * 8, &lV[dbuf][c * 512]); \
    } } while (0)

  ASTAGE(0, 0);
  __syncthreads();

#pragma unroll 2
  for (int kt = 0; kt < 32; ++kt) {
    const int cur = kt & 1;
    if (kt < 31) ASTAGE(cur ^ 1, kt + 1);
    const unsigned short* bufK = lK[cur];
    const unsigned short* bufV = lV[cur];

    // K fragments (shared by both q-blocks)
    bf16x8 kf[4][2];
#pragma unroll
    for (int n = 0; n < 4; ++n)
#pragma unroll
      for (int kk = 0; kk < 2; ++kk) {
        const int ub = (kk * 4 + lk) ^ m7;
        kf[n][kk] = *(const bf16x8*)&bufK[(n * 16 + lr) * 64 + ub * 8];
      }

    // ---- q-block 0: S^T = K @ Q^T -------------------------------------
    f32x4 s0[4];
#pragma unroll
    for (int n = 0; n < 4; ++n) s0[n] = zero;
    __builtin_amdgcn_s_setprio(1);
#pragma unroll
    for (int kk = 0; kk < 2; ++kk)
#pragma unroll
      for (int n = 0; n < 4; ++n)
        s0[n] = __builtin_amdgcn_mfma_f32_16x16x32_bf16(kf[n][kk], qf[0][kk],
                                                        s0[n], 0, 0, 0);
    __builtin_amdgcn_s_setprio(0);
    float ls0 = 0.f;
#pragma unroll
    for (int n = 0; n < 4; ++n) {
      const float p0 = vexp2(s0[n][0]);
      const float p1 = vexp2(s0[n][1]);
      const float p2 = vexp2(s0[n][2]);
      const float p3 = vexp2(s0[n][3]);
      ls0 += (p0 + p1) + (p2 + p3);
      uint2 pv; pv.x = cvtpk(p0, p1); pv.y = cvtpk(p2, p3);
      *(uint2*)&lPw[lr * 64 + (((2 * n + lkh) ^ m7) << 3) + lkb * 4] = pv;
    }
    lrow[0] += ls0;

    // ---- q-block 1 -----------------------------------------------------
    f32x4 s1[4];
#pragma unroll
    for (int n = 0; n < 4; ++n) s1[n] = zero;
    __builtin_amdgcn_s_setprio(1);
#pragma unroll
    for (int kk = 0; kk < 2; ++kk)
#pragma unroll
      for (int n = 0; n < 4; ++n)
        s1[n] = __builtin_amdgcn_mfma_f32_16x16x32_bf16(kf[n][kk], qf[1][kk],
                                                        s1[n], 0, 0, 0);
    __builtin_amdgcn_s_setprio(0);
    float ls1 = 0.f;
    uint2 pw1[4];
#pragma unroll
    for (int n = 0; n < 4; ++n) {
      const float p0 = vexp2(s1[n][0]);
      const float p1 = vexp2(s1[n][1]);
      const float p2 = vexp2(s1[n][2]);
      const float p3 = vexp2(s1[n][3]);
      ls1 += (p0 + p1) + (p2 + p3);
      pw1[n].x = cvtpk(p0, p1); pw1[n].y = cvtpk(p2, p3);
    }
    lrow[1] += ls1;

    // read P0 (write-m0 latency covered by QK-m1), then write P1, read P1
    bf16x8 pf0[2], pf1[2];
#pragma unroll
    for (int kk = 0; kk < 2; ++kk)
      pf0[kk] = *(const bf16x8*)&lPw[lr * 64 + (((kk * 4 + lk) ^ m7) << 3)];
#pragma unroll
    for (int n = 0; n < 4; ++n)
      *(uint2*)&lPw[lr * 64 + (((2 * n + lkh) ^ m7) << 3) + lkb * 4] = pw1[n];
#pragma unroll
    for (int kk = 0; kk < 2; ++kk)
      pf1[kk] = *(const bf16x8*)&lPw[lr * 64 + (((kk * 4 + lk) ^ m7) << 3)];

    // ---- O += P @ V ----------------------------------------------------
    __builtin_amdgcn_s_setprio(1);
#pragma unroll
    for (int n = 0; n < 4; ++n)
#pragma unroll
      for (int kk = 0; kk < 2; ++kk) {
        const int ub = (kk * 4 + lk) ^ m7;
        bf16x8 vf = *(const bf16x8*)&bufV[(n * 16 + lr) * 64 + ub * 8];
        oacc[0][n] = __builtin_amdgcn_mfma_f32_16x16x32_bf16(pf0[kk], vf,
                                                             oacc[0][n], 0, 0, 0);
        oacc[1][n] = __builtin_amdgcn_mfma_f32_16x16x32_bf16(pf1[kk], vf,
                                                             oacc[1][n], 0, 0, 0);
      }
    __builtin_amdgcn_s_setprio(0);

    __syncthreads();
  }
#undef ASTAGE

  // deferred row-sum reduce
  float rinv[2][4];
#pragma unroll
  for (int m = 0; m < 2; ++m) {
    float s = lrow[m];
    s += __shfl_xor(s, 16);
    s += __shfl_xor(s, 32);
#pragma unroll
    for (int r = 0; r < 4; ++r) rinv[m][r] = 1.0f / __shfl(s, lk * 4 + r);
  }

  const int b = bh >> 4, h = bh & 15;
#pragma unroll
  for (int m = 0; m < 2; ++m)
#pragma unroll
    for (int n = 0; n < 4; ++n)
#pragma unroll
      for (int r = 0; r < 4; ++r) {
        const int qrow = q0 + w * 32 + m * 16 + lk * 4 + r;
        const int d = n * 16 + lr;
        Obf[((size_t)b * kSQ + qrow) * kD + h * 64 + d] =
            f2bf(oacc[m][n][r] * rinv[m][r]);
      }
}

// ---------------------------------------------------------------------------
// Kernel 6: t_o = O(bf16) @ out_lora_down
__global__ __launch_bounds__(256) void k_tdown(const unsigned short* __restrict__ Ob,
                                               const float* __restrict__ dn,
                                               float* __restrict__ t_o) {
  const int row = blockIdx.x;
  const int tid = threadIdx.x;
  const unsigned short* src = Ob + (size_t)row * kD;
  short4 v4 = *reinterpret_cast<const short4*>(&src[tid * 4]);
  short vs[4] = {v4.x, v4.y, v4.z, v4.w};
  float a[4] = {0.f, 0.f, 0.f, 0.f};
#pragma unroll
  for (int e = 0; e < 4; ++e) {
    const float x = bf2f((unsigned short)vs[e]);
    const float* dr = dn + (size_t)(tid * 4 + e) * 4;
    a[0] += x * dr[0]; a[1] += x * dr[1]; a[2] += x * dr[2]; a[3] += x * dr[3];
  }
  __shared__ float red[4][4];
  const int l = tid & 63, w = tid >> 6;
#pragma unroll
  for (int k2 = 0; k2 < 4; ++k2) {
    float v = a[k2];
#pragma unroll
    for (int m = 1; m < 64; m <<= 1) v += __shfl_xor(v, m);
    if (l == 0) red[w][k2] = v;
  }
  __syncthreads();
  if (tid < 4)
    t_o[(size_t)row * 4 + tid] = red[0][tid] + red[1][tid] + red[2][tid] + red[3][tid];
}

// ---------------------------------------------------------------------------
extern "C" void kernel_launch(void* const* d_in, const int* in_sizes, int n_in,
                              void* d_out, int out_size, void* d_ws, size_t ws_size,
                              hipStream_t stream) {
  (void)in_sizes; (void)n_in; (void)out_size; (void)ws_size;
  const float* hs   = (const float*)d_in[0];
  const float* enc  = (const float*)d_in[1];
  const float* Wq   = (const float*)d_in[2];
  const float* Wk   = (const float*)d_in[3];
  const float* Wv   = (const float*)d_in[4];
  const float* Wo   = (const float*)d_in[5];
  const float* bo   = (const float*)d_in[6];
  const float* q_dn = (const float*)d_in[7];
  const float* q_up = (const float*)d_in[8];
  const float* k_dn = (const float*)d_in[9];
  const float* k_up = (const float*)d_in[10];
  const float* v_dn = (const float*)d_in[11];
  const float* v_up = (const float*)d_in[12];
  const float* o_dn = (const float*)d_in[13];
  const float* o_up = (const float*)d_in[14];

  char* ws = (char*)d_ws;
  size_t off = 0;
  auto alloc = [&](size_t bytes) -> void* {
    void* p = ws + off;
    off += (bytes + 255) & ~(size_t)255;
    return p;
  };
  const size_t ACT = (size_t)kM * kD * 2;
  unsigned short* hsb  = (unsigned short*)alloc(ACT);
  unsigned short* encb = (unsigned short*)alloc(ACT);
  unsigned short* Wqt  = (unsigned short*)alloc((size_t)1024 * 1024 * 2);
  unsigned short* Wkvt = (unsigned short*)alloc((size_t)2048 * 1024 * 2);
  unsigned short* Wot  = (unsigned short*)alloc((size_t)1024 * 1024 * 2);
  unsigned short* Qhp  = (unsigned short*)alloc(ACT);
  unsigned short* Khp  = (unsigned short*)alloc(ACT);
  unsigned short* Vhp  = (unsigned short*)alloc(ACT);
  float* tq  = (float*)alloc((size_t)kM * 4 * 4);
  float* tkv = (float*)alloc((size_t)kM * 8 * 4);
  float* to  = (float*)alloc((size_t)kM * 4 * 4);
  unsigned short* Vtt = hsb;   // alias: V^T reuses hidden bf16 buffer
  unsigned short* Ob  = encb;  // alias: attention O reuses encoder bf16 buffer

  k_prep_wt<<<dim3(2 * kM + 1024), dim3(256), 0, stream>>>(
      hs, enc, q_dn, k_dn, v_dn, Wq, Wk, Wv, Wo,
      hsb, encb, tq, tkv, Wqt, Wkvt, Wot);

  k_gemm_qkv<<<dim3(1536), dim3(256), 0, stream>>>(
      hsb, encb, Wqt, Wkvt, tq, tkv, q_up, k_up, v_up, Qhp, Khp, Vhp);

  k_vt<<<dim3(32, 64), dim3(256), 0, stream>>>(Vhp, Vtt);
  k_attn<<<dim3(16, 64), dim3(256), 0, stream>>>(Qhp, Khp, Vtt, Ob);
  k_tdown<<<dim3(kM), dim3(256), 0, stream>>>(Ob, o_dn, to);

  k_gemm_out<<<dim3(512), dim3(256), 0, stream>>>(Ob, Wot, to, o_up, bo,
                                                  (float*)d_out);
}

// Round 6
// 327.089 us; speedup vs baseline: 1.5240x; 1.5240x over previous
//
#include <hip/hip_runtime.h>
#include <hip/hip_bf16.h>

typedef __attribute__((ext_vector_type(8))) short bf16x8;
typedef __attribute__((ext_vector_type(4))) float f32x4;

#define DEVFN static __device__ __forceinline__

constexpr int kSQ = 2048, kSKV = 2048, kD = 1024, kH = 16;
constexpr int kM = 4 * kSQ;   // 8192 query rows (B*SQ)

DEVFN unsigned short f2bf(float f) {
  union { float f; unsigned u; } v; v.f = f;
  unsigned r = v.u + 0x7FFFu + ((v.u >> 16) & 1u);
  return (unsigned short)(r >> 16);
}
DEVFN float bf2f(unsigned short h) {
  union { unsigned u; float f; } v; v.u = ((unsigned)h) << 16; return v.f;
}
DEVFN unsigned cvtpk(float lo, float hi) {
  unsigned r;
  asm("v_cvt_pk_bf16_f32 %0, %1, %2" : "=v"(r) : "v"(lo), "v"(hi));
  return r;
}
DEVFN float vexp2(float x) {
  float r;
  asm("v_exp_f32 %0, %1" : "=v"(r) : "v"(x));
  return r;
}

DEVFN void gload16(const void* g, void* l) {
  __builtin_amdgcn_global_load_lds(
      (const __attribute__((address_space(1))) unsigned int*)g,
      (__attribute__((address_space(3))) unsigned int*)l, 16, 0, 0);
}

// counted-vmcnt pipeline waits (T4)
#define PIPE_WAIT(last, n)                                        \
  do {                                                            \
    if (last) asm volatile("s_waitcnt vmcnt(0)" ::: "memory");    \
    else      asm volatile("s_waitcnt vmcnt(" #n ")" ::: "memory"); \
    __builtin_amdgcn_s_barrier();                                 \
    asm volatile("" ::: "memory");                                \
  } while (0)
#define PIPE_FREE()                                               \
  do {                                                            \
    asm volatile("s_waitcnt lgkmcnt(0)" ::: "memory");            \
    __builtin_amdgcn_s_barrier();                                 \
    asm volatile("" ::: "memory");                                \
  } while (0)

// ---------------------------------------------------------------------------
// Kernel 1 (merged): blocks [0, 2*kM): activation fp32->bf16 + LoRA-down dots.
// blocks [2*kM, 2*kM+1024): weight convert+transpose (4 weights x 256 tiles).
__global__ __launch_bounds__(256) void k_prep_wt(
    const float* __restrict__ hs, const float* __restrict__ enc,
    const float* __restrict__ qdn, const float* __restrict__ kdn,
    const float* __restrict__ vdn,
    const float* __restrict__ Wq, const float* __restrict__ Wk,
    const float* __restrict__ Wv, const float* __restrict__ Wo,
    unsigned short* __restrict__ hsb, unsigned short* __restrict__ encb,
    float* __restrict__ tq, float* __restrict__ tkv,
    unsigned short* __restrict__ Wqt, unsigned short* __restrict__ Wkvt,
    unsigned short* __restrict__ Wot) {
  __shared__ float red[4][8];
  __shared__ unsigned short tile[64][65];
  const int bid = blockIdx.x;
  const int tid = threadIdx.x;

  if (bid < 2 * kM) {
    const bool isH = bid < kM;
    const int rr = isH ? bid : bid - kM;
    const float* srcRow = (isH ? hs : enc) + (size_t)rr * kD;
    unsigned short* dstRow = (isH ? hsb : encb) + (size_t)rr * kD;

    float4 x = reinterpret_cast<const float4*>(srcRow)[tid];
    short4 o;
    o.x = (short)f2bf(x.x); o.y = (short)f2bf(x.y);
    o.z = (short)f2bf(x.z); o.w = (short)f2bf(x.w);
    *reinterpret_cast<short4*>(dstRow + tid * 4) = o;

    float xs[4] = {x.x, x.y, x.z, x.w};
    float a[4] = {0.f, 0.f, 0.f, 0.f};
    float bacc[4] = {0.f, 0.f, 0.f, 0.f};
    const float* dnA = isH ? qdn : kdn;
    const int base = tid * 4;
#pragma unroll
    for (int e = 0; e < 4; ++e) {
      const float* dr = dnA + (size_t)(base + e) * 4;
      a[0] += xs[e] * dr[0]; a[1] += xs[e] * dr[1];
      a[2] += xs[e] * dr[2]; a[3] += xs[e] * dr[3];
    }
    if (!isH) {
#pragma unroll
      for (int e = 0; e < 4; ++e) {
        const float* dr = vdn + (size_t)(base + e) * 4;
        bacc[0] += xs[e] * dr[0]; bacc[1] += xs[e] * dr[1];
        bacc[2] += xs[e] * dr[2]; bacc[3] += xs[e] * dr[3];
      }
    }
    const int l = tid & 63, w = tid >> 6;
    float vals[8] = {a[0], a[1], a[2], a[3], bacc[0], bacc[1], bacc[2], bacc[3]};
#pragma unroll
    for (int k2 = 0; k2 < 8; ++k2) {
      float v = vals[k2];
#pragma unroll
      for (int m = 1; m < 64; m <<= 1) v += __shfl_xor(v, m);
      if (l == 0) red[w][k2] = v;
    }
    __syncthreads();
    if (tid < 8) {
      float s = red[0][tid] + red[1][tid] + red[2][tid] + red[3][tid];
      if (isH) {
        if (tid < 4) tq[(size_t)rr * 4 + tid] = s;
      } else {
        tkv[(size_t)rr * 8 + tid] = s;   // 0..3 = k-down, 4..7 = v-down
      }
    }
  } else {
    const int t = bid - 2 * kM;
    const int wid = t >> 8, tt = t & 255;
    const float* W = (wid == 0) ? Wq : (wid == 1) ? Wk : (wid == 2) ? Wv : Wo;
    unsigned short* Wt = (wid == 0) ? Wqt : (wid == 1) ? Wkvt
                        : (wid == 2) ? (Wkvt + (size_t)1024 * 1024) : Wot;
    const int tk0 = (tt & 15) * 64;
    const int tn0 = (tt >> 4) * 64;
    for (int i = tid; i < 4096; i += 256) {
      int r = i >> 6, c = i & 63;
      tile[r][c] = f2bf(W[(size_t)(tk0 + r) * 1024 + tn0 + c]);
    }
    __syncthreads();
    for (int i = tid; i < 4096; i += 256) {
      int r = i >> 6, c = i & 63;
      Wt[(size_t)(tn0 + r) * 1024 + tk0 + c] = tile[c][r];
    }
  }
}

// ---------------------------------------------------------------------------
// Big-tile GEMM core: BM=256, BN=128, BK=64, 8 waves (512 thr), 96KB LDS
// double-buffer, counted vmcnt(6), T2 XOR swizzle (16B unit ^= row&7) applied
// via pre-swizzled global source + swizzled ds_read (both-sides pattern).
// Per wave: 128x32 output = acc[8][2] f32x4; 32 MFMAs per K-step.

// stage A-tile (256x64) + B-tile (128x64) for K-step kt into buffer dbuf.
// 6 gload16 per thread per stage (A:4, B:2).
#define GSTAGE(dbuf, kt) do {                                                 \
    _Pragma("unroll")                                                         \
    for (int j = 0; j < 4; ++j) {                                             \
      const int s = (j * 8 + w) * 64 + l;                                     \
      const int row = s >> 3, u = s & 7;                                      \
      gload16(Ap + (size_t)row * 1024 + (kt) * 64 + ((u ^ (row & 7)) * 8),    \
              &lA[dbuf][(j * 8 + w) * 512]);                                  \
    }                                                                         \
    _Pragma("unroll")                                                         \
    for (int j = 0; j < 2; ++j) {                                             \
      const int s = (j * 8 + w) * 64 + l;                                     \
      const int row = s >> 3, u = s & 7;                                      \
      gload16(Bp + (size_t)row * 1024 + (kt) * 64 + ((u ^ (row & 7)) * 8),    \
              &lB[dbuf][(j * 8 + w) * 512]);                                  \
    } } while (0)

#define BIG_GEMM_LOOP()                                                       \
  GSTAGE(0, 0);                                                               \
  GSTAGE(1, 1);                                                               \
  _Pragma("unroll 2")                                                         \
  for (int kt = 0; kt < 16; ++kt) {                                           \
    const int cur = kt & 1;                                                   \
    PIPE_WAIT(kt == 15, 6);                                                   \
    _Pragma("unroll")                                                         \
    for (int kk = 0; kk < 2; ++kk) {                                          \
      bf16x8 af[8], bfr[2];                                                   \
      _Pragma("unroll")                                                       \
      for (int m = 0; m < 8; ++m) {                                           \
        const int ar = wr + m * 16 + lr;                                      \
        af[m] = *(const bf16x8*)&lA[cur][ar * 64 +                            \
                 (((kk * 4 + lk) ^ (ar & 7)) * 8)];                           \
      }                                                                       \
      _Pragma("unroll")                                                       \
      for (int n = 0; n < 2; ++n) {                                           \
        const int br = wc + n * 16 + lr;                                      \
        bfr[n] = *(const bf16x8*)&lB[cur][br * 64 +                           \
                 (((kk * 4 + lk) ^ (br & 7)) * 8)];                           \
      }                                                                       \
      _Pragma("unroll")                                                       \
      for (int m = 0; m < 8; ++m)                                             \
        _Pragma("unroll")                                                     \
        for (int n = 0; n < 2; ++n)                                           \
          acc[m][n] = __builtin_amdgcn_mfma_f32_16x16x32_bf16(                \
              af[m], bfr[n], acc[m][n], 0, 0, 0);                             \
    }                                                                         \
    PIPE_FREE();                                                              \
    if (kt < 14) GSTAGE(cur, kt + 2);                                         \
  }

// Kernel 2: QKV projection. blocks [0,256): Q (N=1024); [256,768): K|V (N=2048,
// A=encb shared). XCD-swizzled within each segment.
__global__ __launch_bounds__(512) void k_gemm_qkv(
    const unsigned short* __restrict__ hsb, const unsigned short* __restrict__ encb,
    const unsigned short* __restrict__ Wqt, const unsigned short* __restrict__ Wkvt,
    const float* __restrict__ tq, const float* __restrict__ tkv,
    const float* __restrict__ q_up, const float* __restrict__ k_up,
    const float* __restrict__ v_up,
    unsigned short* __restrict__ Qhp, unsigned short* __restrict__ Khp,
    unsigned short* __restrict__ Vhp) {
  __shared__ unsigned short lA[2][256 * 64];
  __shared__ unsigned short lB[2][128 * 64];
  const int tid = threadIdx.x;
  const int l = tid & 63, w = tid >> 6;
  const int bid = blockIdx.x;

  const unsigned short *A, *Bt;
  const float *tmat, *up;
  unsigned short* dst;
  int m0, nB0, nOut0, tstr;
  if (bid < 256) {
    const int rid = (bid & 7) * 32 + (bid >> 3);
    m0 = (rid >> 3) * 256; nB0 = (rid & 7) * 128;
    A = hsb; Bt = Wqt; tmat = tq; tstr = 4; up = q_up; dst = Qhp; nOut0 = nB0;
  } else {
    const int b2 = bid - 256;
    const int rid = (b2 & 7) * 64 + (b2 >> 3);
    m0 = (rid >> 4) * 256; nB0 = (rid & 15) * 128;
    A = encb; Bt = Wkvt; tstr = 8;
    if (nB0 < 1024) { tmat = tkv;     up = k_up; dst = Khp; nOut0 = nB0; }
    else            { tmat = tkv + 4; up = v_up; dst = Vhp; nOut0 = nB0 - 1024; }
  }
  const int wr = (w >> 2) * 128, wc = (w & 3) * 32;
  const int lr = l & 15, lk = l >> 4;
  const unsigned short* Ap = A  + (size_t)m0  * 1024;
  const unsigned short* Bp = Bt + (size_t)nB0 * 1024;

  f32x4 acc[8][2];
  const f32x4 zero = {0.f, 0.f, 0.f, 0.f};
#pragma unroll
  for (int m = 0; m < 8; ++m)
#pragma unroll
    for (int n = 0; n < 2; ++n) acc[m][n] = zero;

  BIG_GEMM_LOOP()

#pragma unroll
  for (int n = 0; n < 2; ++n) {
    const int gcol = nOut0 + wc + n * 16 + lr;
    const float u0 = up[gcol], u1 = up[1024 + gcol];
    const float u2 = up[2048 + gcol], u3 = up[3072 + gcol];
    const int h = gcol >> 6, d = gcol & 63;
#pragma unroll
    for (int m = 0; m < 8; ++m) {
#pragma unroll
      for (int r = 0; r < 4; ++r) {
        const int grow = m0 + wr + m * 16 + lk * 4 + r;
        const float4 tt = *reinterpret_cast<const float4*>(tmat + (size_t)grow * tstr);
        const float val = acc[m][n][r] + tt.x * u0 + tt.y * u1 + tt.z * u2 + tt.w * u3;
        const int b = grow >> 11, s = grow & 2047;
        dst[(((size_t)(b * kH + h)) * 2048 + s) * 64 + d] = f2bf(val);
      }
    }
  }
}

// Kernel 3: final GEMM  out = Ob @ Wot^T + bias + t_o @ o_up  (f32 output)
__global__ __launch_bounds__(512) void k_gemm_out(
    const unsigned short* __restrict__ A, const unsigned short* __restrict__ Bt,
    const float* __restrict__ tmat, const float* __restrict__ up,
    const float* __restrict__ bias, float* __restrict__ outp) {
  __shared__ unsigned short lA[2][256 * 64];
  __shared__ unsigned short lB[2][128 * 64];
  const int tid = threadIdx.x;
  const int l = tid & 63, w = tid >> 6;
  const int bid = blockIdx.x;
  const int rid = (bid & 7) * 32 + (bid >> 3);
  const int m0 = (rid >> 3) * 256, nB0 = (rid & 7) * 128;
  const int wr = (w >> 2) * 128, wc = (w & 3) * 32;
  const int lr = l & 15, lk = l >> 4;
  const unsigned short* Ap = A  + (size_t)m0  * 1024;
  const unsigned short* Bp = Bt + (size_t)nB0 * 1024;

  f32x4 acc[8][2];
  const f32x4 zero = {0.f, 0.f, 0.f, 0.f};
#pragma unroll
  for (int m = 0; m < 8; ++m)
#pragma unroll
    for (int n = 0; n < 2; ++n) acc[m][n] = zero;

  BIG_GEMM_LOOP()

#pragma unroll
  for (int n = 0; n < 2; ++n) {
    const int gcol = nB0 + wc + n * 16 + lr;
    const float u0 = up[gcol], u1 = up[1024 + gcol];
    const float u2 = up[2048 + gcol], u3 = up[3072 + gcol];
    const float bz = bias[gcol];
#pragma unroll
    for (int m = 0; m < 8; ++m) {
#pragma unroll
      for (int r = 0; r < 4; ++r) {
        const int grow = m0 + wr + m * 16 + lk * 4 + r;
        const float4 tt = *reinterpret_cast<const float4*>(tmat + (size_t)grow * 4);
        outp[(size_t)grow * 1024 + gcol] =
            acc[m][n][r] + tt.x * u0 + tt.y * u1 + tt.z * u2 + tt.w * u3 + bz;
      }
    }
  }
}

// ---------------------------------------------------------------------------
// Kernel 4: V head-layout transpose: (bh, s, d) -> (bh, d, s)
__global__ __launch_bounds__(256) void k_vt(const unsigned short* __restrict__ Vh,
                                            unsigned short* __restrict__ Vt) {
  __shared__ unsigned short tile[64][65];
  const int bh = blockIdx.y;
  const int s0 = blockIdx.x * 64;
  const unsigned short* src = Vh + ((size_t)bh * kSKV + s0) * 64;
  for (int i = threadIdx.x; i < 4096; i += 256) {
    int r = i >> 6, c = i & 63;
    tile[r][c] = src[(size_t)r * 64 + c];
  }
  __syncthreads();
  unsigned short* dst = Vt + (size_t)bh * 64 * kSKV + s0;
  for (int i = threadIdx.x; i < 4096; i += 256) {
    int r = i >> 6, c = i & 63;
    dst[(size_t)r * kSKV + c] = tile[c][r];
  }
}

// ---------------------------------------------------------------------------
// Kernel 5: flash attention, QBLK=128 (4 waves x 32 q-rows), KV tiles of 64.
// Fixed-max softmax via exp2 (Q pre-scaled by log2e/8). Conflict-free
// 16B-unit XOR swizzle on K/V/P. (round-3 structure: dbuf + syncthreads)
__global__ __launch_bounds__(256) void k_attn(
    const unsigned short* __restrict__ Qh, const unsigned short* __restrict__ Kh,
    const unsigned short* __restrict__ Vt, unsigned short* __restrict__ Obf) {
  __shared__ unsigned short lK[2][4096];
  __shared__ unsigned short lV[2][4096];
  __shared__ __align__(16) unsigned short lP[4][1024];

  const int bid = blockIdx.x + 16 * blockIdx.y;              // 1024 blocks
  const int rid = (bid & 7) * 128 + (bid >> 3);
  const int q0 = (rid & 15) * 128;
  const int bh = rid >> 4;

  const int tid = threadIdx.x;
  const int l = tid & 63, w = tid >> 6;
  const int lr = l & 15, lk = l >> 4;
  const int m7 = lr & 7;
  const int lkh = lk >> 1, lkb = lk & 1;

  const unsigned short* Qb = Qh + (size_t)bh * kSQ * 64;
  const unsigned short* Kb = Kh + (size_t)bh * kSKV * 64;
  const unsigned short* Vb = Vt + (size_t)bh * 64 * kSKV;

  // Q fragments pre-scaled by log2(e)/8 (exp2-form softmax)
  const float QS = 0.125f * 1.4426950408889634f;
  bf16x8 qf[2][2];
#pragma unroll
  for (int m = 0; m < 2; ++m)
#pragma unroll
    for (int kk = 0; kk < 2; ++kk) {
      bf16x8 v = *(const bf16x8*)
          &Qb[(size_t)(q0 + w * 32 + m * 16 + lr) * 64 + kk * 32 + lk * 8];
#pragma unroll
      for (int j = 0; j < 8; ++j) {
        unsigned short u = (unsigned short)v[j];
        v[j] = (short)f2bf(bf2f(u) * QS);
      }
      qf[m][kk] = v;
    }

  f32x4 oacc[2][4];
  const f32x4 zero = {0.f, 0.f, 0.f, 0.f};
#pragma unroll
  for (int m = 0; m < 2; ++m)
#pragma unroll
    for (int n = 0; n < 4; ++n) oacc[m][n] = zero;
  float lrow[2] = {0.f, 0.f};

  const int sr8 = l >> 3;
  const int su = (l & 7) ^ sr8;
  unsigned short* lPw = lP[w];

#define ASTAGE(dbuf, tile) do { \
    _Pragma("unroll") for (int cc = 0; cc < 2; ++cc) { \
      const int c = 2 * w + cc; const int row = c * 8 + sr8; \
      gload16(Kb + (size_t)((tile) * 64 + row) * 64 + su * 8, &lK[dbuf][c * 512]); \
      gload16(Vb + (size_t)row * kSKV + (tile) * 64 + su * 8, &lV[dbuf][c * 512]); \
    } } while (0)

  ASTAGE(0, 0);
  __syncthreads();

#pragma unroll 2
  for (int kt = 0; kt < 32; ++kt) {
    const int cur = kt & 1;
    if (kt < 31) ASTAGE(cur ^ 1, kt + 1);
    const unsigned short* bufK = lK[cur];
    const unsigned short* bufV = lV[cur];

    // K fragments (shared by both q-blocks)
    bf16x8 kf[4][2];
#pragma unroll
    for (int n = 0; n < 4; ++n)
#pragma unroll
      for (int kk = 0; kk < 2; ++kk) {
        const int ub = (kk * 4 + lk) ^ m7;
        kf[n][kk] = *(const bf16x8*)&bufK[(n * 16 + lr) * 64 + ub * 8];
      }

    // ---- q-block 0: S^T = K @ Q^T -------------------------------------
    f32x4 s0[4];
#pragma unroll
    for (int n = 0; n < 4; ++n) s0[n] = zero;
    __builtin_amdgcn_s_setprio(1);
#pragma unroll
    for (int kk = 0; kk < 2; ++kk)
#pragma unroll
      for (int n = 0; n < 4; ++n)
        s0[n] = __builtin_amdgcn_mfma_f32_16x16x32_bf16(kf[n][kk], qf[0][kk],
                                                        s0[n], 0, 0, 0);
    __builtin_amdgcn_s_setprio(0);
    float ls0 = 0.f;
#pragma unroll
    for (int n = 0; n < 4; ++n) {
      const float p0 = vexp2(s0[n][0]);
      const float p1 = vexp2(s0[n][1]);
      const float p2 = vexp2(s0[n][2]);
      const float p3 = vexp2(s0[n][3]);
      ls0 += (p0 + p1) + (p2 + p3);
      uint2 pv; pv.x = cvtpk(p0, p1); pv.y = cvtpk(p2, p3);
      *(uint2*)&lPw[lr * 64 + (((2 * n + lkh) ^ m7) << 3) + lkb * 4] = pv;
    }
    lrow[0] += ls0;

    // ---- q-block 1 -----------------------------------------------------
    f32x4 s1[4];
#pragma unroll
    for (int n = 0; n < 4; ++n) s1[n] = zero;
    __builtin_amdgcn_s_setprio(1);
#pragma unroll
    for (int kk = 0; kk < 2; ++kk)
#pragma unroll
      for (int n = 0; n < 4; ++n)
        s1[n] = __builtin_amdgcn_mfma_f32_16x16x32_bf16(kf[n][kk], qf[1][kk],
                                                        s1[n], 0, 0, 0);
    __builtin_amdgcn_s_setprio(0);
    float ls1 = 0.f;
    uint2 pw1[4];
#pragma unroll
    for (int n = 0; n < 4; ++n) {
      const float p0 = vexp2(s1[n][0]);
      const float p1 = vexp2(s1[n][1]);
      const float p2 = vexp2(s1[n][2]);
      const float p3 = vexp2(s1[n][3]);
      ls1 += (p0 + p1) + (p2 + p3);
      pw1[n].x = cvtpk(p0, p1); pw1[n].y = cvtpk(p2, p3);
    }
    lrow[1] += ls1;

    // read P0 (write-m0 latency covered by QK-m1), then write P1, read P1
    bf16x8 pf0[2], pf1[2];
#pragma unroll
    for (int kk = 0; kk < 2; ++kk)
      pf0[kk] = *(const bf16x8*)&lPw[lr * 64 + (((kk * 4 + lk) ^ m7) << 3)];
#pragma unroll
    for (int n = 0; n < 4; ++n)
      *(uint2*)&lPw[lr * 64 + (((2 * n + lkh) ^ m7) << 3) + lkb * 4] = pw1[n];
#pragma unroll
    for (int kk = 0; kk < 2; ++kk)
      pf1[kk] = *(const bf16x8*)&lPw[lr * 64 + (((kk * 4 + lk) ^ m7) << 3)];

    // ---- O += P @ V ----------------------------------------------------
    __builtin_amdgcn_s_setprio(1);
#pragma unroll
    for (int n = 0; n < 4; ++n)
#pragma unroll
      for (int kk = 0; kk < 2; ++kk) {
        const int ub = (kk * 4 + lk) ^ m7;
        bf16x8 vf = *(const bf16x8*)&bufV[(n * 16 + lr) * 64 + ub * 8];
        oacc[0][n] = __builtin_amdgcn_mfma_f32_16x16x32_bf16(pf0[kk], vf,
                                                             oacc[0][n], 0, 0, 0);
        oacc[1][n] = __builtin_amdgcn_mfma_f32_16x16x32_bf16(pf1[kk], vf,
                                                             oacc[1][n], 0, 0, 0);
      }
    __builtin_amdgcn_s_setprio(0);

    __syncthreads();
  }
#undef ASTAGE

  // deferred row-sum reduce
  float rinv[2][4];
#pragma unroll
  for (int m = 0; m < 2; ++m) {
    float s = lrow[m];
    s += __shfl_xor(s, 16);
    s += __shfl_xor(s, 32);
#pragma unroll
    for (int r = 0; r < 4; ++r) rinv[m][r] = 1.0f / __shfl(s, lk * 4 + r);
  }

  const int b = bh >> 4, h = bh & 15;
#pragma unroll
  for (int m = 0; m < 2; ++m)
#pragma unroll
    for (int n = 0; n < 4; ++n)
#pragma unroll
      for (int r = 0; r < 4; ++r) {
        const int qrow = q0 + w * 32 + m * 16 + lk * 4 + r;
        const int d = n * 16 + lr;
        Obf[((size_t)b * kSQ + qrow) * kD + h * 64 + d] =
            f2bf(oacc[m][n][r] * rinv[m][r]);
      }
}

// ---------------------------------------------------------------------------
// Kernel 6: t_o = O(bf16) @ out_lora_down
__global__ __launch_bounds__(256) void k_tdown(const unsigned short* __restrict__ Ob,
                                               const float* __restrict__ dn,
                                               float* __restrict__ t_o) {
  const int row = blockIdx.x;
  const int tid = threadIdx.x;
  const unsigned short* src = Ob + (size_t)row * kD;
  short4 v4 = *reinterpret_cast<const short4*>(&src[tid * 4]);
  short vs[4] = {v4.x, v4.y, v4.z, v4.w};
  float a[4] = {0.f, 0.f, 0.f, 0.f};
#pragma unroll
  for (int e = 0; e < 4; ++e) {
    const float x = bf2f((unsigned short)vs[e]);
    const float* dr = dn + (size_t)(tid * 4 + e) * 4;
    a[0] += x * dr[0]; a[1] += x * dr[1]; a[2] += x * dr[2]; a[3] += x * dr[3];
  }
  __shared__ float red[4][4];
  const int l = tid & 63, w = tid >> 6;
#pragma unroll
  for (int k2 = 0; k2 < 4; ++k2) {
    float v = a[k2];
#pragma unroll
    for (int m = 1; m < 64; m <<= 1) v += __shfl_xor(v, m);
    if (l == 0) red[w][k2] = v;
  }
  __syncthreads();
  if (tid < 4)
    t_o[(size_t)row * 4 + tid] = red[0][tid] + red[1][tid] + red[2][tid] + red[3][tid];
}

// ---------------------------------------------------------------------------
extern "C" void kernel_launch(void* const* d_in, const int* in_sizes, int n_in,
                              void* d_out, int out_size, void* d_ws, size_t ws_size,
                              hipStream_t stream) {
  (void)in_sizes; (void)n_in; (void)out_size; (void)ws_size;
  const float* hs   = (const float*)d_in[0];
  const float* enc  = (const float*)d_in[1];
  const float* Wq   = (const float*)d_in[2];
  const float* Wk   = (const float*)d_in[3];
  const float* Wv   = (const float*)d_in[4];
  const float* Wo   = (const float*)d_in[5];
  const float* bo   = (const float*)d_in[6];
  const float* q_dn = (const float*)d_in[7];
  const float* q_up = (const float*)d_in[8];
  const float* k_dn = (const float*)d_in[9];
  const float* k_up = (const float*)d_in[10];
  const float* v_dn = (const float*)d_in[11];
  const float* v_up = (const float*)d_in[12];
  const float* o_dn = (const float*)d_in[13];
  const float* o_up = (const float*)d_in[14];

  char* ws = (char*)d_ws;
  size_t off = 0;
  auto alloc = [&](size_t bytes) -> void* {
    void* p = ws + off;
    off += (bytes + 255) & ~(size_t)255;
    return p;
  };
  const size_t ACT = (size_t)kM * kD * 2;
  unsigned short* hsb  = (unsigned short*)alloc(ACT);
  unsigned short* encb = (unsigned short*)alloc(ACT);
  unsigned short* Wqt  = (unsigned short*)alloc((size_t)1024 * 1024 * 2);
  unsigned short* Wkvt = (unsigned short*)alloc((size_t)2048 * 1024 * 2);
  unsigned short* Wot  = (unsigned short*)alloc((size_t)1024 * 1024 * 2);
  unsigned short* Qhp  = (unsigned short*)alloc(ACT);
  unsigned short* Khp  = (unsigned short*)alloc(ACT);
  unsigned short* Vhp  = (unsigned short*)alloc(ACT);
  float* tq  = (float*)alloc((size_t)kM * 4 * 4);
  float* tkv = (float*)alloc((size_t)kM * 8 * 4);
  float* to  = (float*)alloc((size_t)kM * 4 * 4);
  unsigned short* Vtt = hsb;   // alias: V^T reuses hidden bf16 buffer
  unsigned short* Ob  = encb;  // alias: attention O reuses encoder bf16 buffer

  k_prep_wt<<<dim3(2 * kM + 1024), dim3(256), 0, stream>>>(
      hs, enc, q_dn, k_dn, v_dn, Wq, Wk, Wv, Wo,
      hsb, encb, tq, tkv, Wqt, Wkvt, Wot);

  k_gemm_qkv<<<dim3(768), dim3(512), 0, stream>>>(
      hsb, encb, Wqt, Wkvt, tq, tkv, q_up, k_up, v_up, Qhp, Khp, Vhp);

  k_vt<<<dim3(32, 64), dim3(256), 0, stream>>>(Vhp, Vtt);
  k_attn<<<dim3(16, 64), dim3(256), 0, stream>>>(Qhp, Khp, Vtt, Ob);
  k_tdown<<<dim3(kM), dim3(256), 0, stream>>>(Ob, o_dn, to);

  k_gemm_out<<<dim3(256), dim3(512), 0, stream>>>(Ob, Wot, to, o_up, bo,
                                                  (float*)d_out);
}